// Round 3
// baseline (177.565 us; speedup 1.0000x reference)
//
#include <hip/hip_runtime.h>
#include <hip/hip_bf16.h>
#include <stdint.h>
#include <stddef.h>

#define B_   16
#define N_   6272     // T*H*W = 32*14*14
#define C_   512
#define K_   64
#define NBC  16       // rows per chunk
#define SLICES 28     // blocks per batch
#define CHUNKS 14     // 28*14*16 = 6272

#define WKT_BYTES   ((size_t)K_ * C_ * sizeof(uint16_t))          // 64 KB
#define SUMWS_OFF   WKT_BYTES
#define SUMWS_BYTES ((size_t)B_ * K_ * sizeof(float))             // 4 KB
#define PART_OFF    (0x11000u)                                    // 68 KB, 4KB-aligned
#define PART_ELEMS  ((size_t)SLICES * B_ * C_ * K_)               // bf16 elements
#define WS_NEEDED   (PART_OFF + PART_ELEMS * sizeof(uint16_t))    // ~29.4 MB

typedef float f32x4 __attribute__((ext_vector_type(4)));
typedef short bf16x8 __attribute__((ext_vector_type(8)));
typedef uint32_t u32x2 __attribute__((ext_vector_type(2)));

__device__ __forceinline__ uint32_t cvt2(float lo, float hi) {
    __hip_bfloat162 h = __float22bfloat162_rn(float2{lo, hi});
    union { __hip_bfloat162 h; uint32_t u; } v; v.h = h;
    return v.u;
}

__device__ __forceinline__ short f32_bf16(float f) {
    union { float f; uint32_t u; } v; v.f = f;
    return (short)((v.u + 0x7FFFu + ((v.u >> 16) & 1u)) >> 16);  // RNE
}

__device__ __forceinline__ float bf16_f32(uint16_t u) {
    union { uint32_t u; float f; } v; v.u = (uint32_t)u << 16;
    return v.f;
}

// LDS-only barrier: drains lgkm (ds ops) but leaves global loads in flight.
// The "memory" clobbers also fence LICM: the per-chunk bq reloads cannot be
// hoisted out of the loop across these barriers (R3: bq demoted from
// persistent regs to per-chunk L2 reloads for the 128-VGPR diet).
__device__ __forceinline__ void bar_lds() {
    asm volatile("s_waitcnt lgkmcnt(0)" ::: "memory");
    __builtin_amdgcn_s_barrier();
    asm volatile("" ::: "memory");
    __builtin_amdgcn_sched_barrier(0);
}

// swizzled LDS byte offset of bf16 element x[n][c] within a 16-row buffer:
//   byte = (n*1024 + c*2) ^ ((n&7)<<4) ^ (((n>>3)&1)<<6)

// ---- prep: WkT[k][c] = bf16(kernel[c][k]) ----
__global__ void prep_wkt(const float* __restrict__ kern, uint16_t* __restrict__ wkt) {
    int idx = blockIdx.x * blockDim.x + threadIdx.x;   // 0..32767
    int k = idx >> 9, c = idx & 511;
    wkt[idx] = (uint16_t)f32_bf16(kern[c * K_ + k]);
}

// ---- main fused kernel: 8 waves, dbuf LDS, 2 blocks/CU (R3) ----
// launch_bounds(512,4): 4 waves/EU -> 2 blocks/CU -> all 448 blocks resident
// in ONE dispatch round (was 2 rounds at 1 block/CU with (512,2)), and
// anti-phase co-resident blocks hide each other's barrier/softmax stalls.
// Register diet to fit 128 VGPR: bq reloaded per-chunk from L2, stg split
// 2+2, GEMM2 mf-outer (1 live A-frag).
template <bool STORE_PARTIALS>
__global__ __launch_bounds__(512, 4)
void vlad_main(const float* __restrict__ x, const uint16_t* __restrict__ wkt,
               const float* __restrict__ bias, float* __restrict__ out,
               float* __restrict__ sum_ws, uint16_t* __restrict__ partials)
{
    const int b = blockIdx.x, slice = blockIdx.y;
    const int tid = threadIdx.x;
    const int w    = tid >> 6;       // wave 0..7
    const int lane = tid & 63;
    const int g = lane & 15, q = lane >> 4;
    const int wr = w >> 2;           // C-half for GEMM1 (0: ch 0..255, 1: 256..511)
    const int wc = w & 3;            // cluster group for GEMM1

    // xs FIRST: tr-read asm assumes LDS offset 0 for xs (verified R3/R4)
    __shared__ __align__(16) uint8_t  xs[2][NBC * 1024];   // 2 x 16KB swizzled bf16
    __shared__ __align__(16) uint16_t assgnT[K_][NBC];     // [cluster][row] bf16, 2KB
    __shared__ __align__(16) float    red1[NBC][K_];       // partial logits, 4KB
    __shared__ __align__(16) float    red[NBC][4];         // row softmax sums

    const float* xb = x + (size_t)b * N_ * C_;

    // GEMM1 B-frag base: WkT[wc*16+g][wr*256 + ks*32 + q*8 ..+8]; loads are
    // per-chunk (L2-resident 64KB, shared by all blocks) to save 32 VGPRs.
    const uint16_t* wp = wkt + (size_t)(wc * 16 + g) * C_ + wr * 256 + q * 8;

    f32x4 acc2[4][4];   // [mf: clusters 16mf..][nf: channels w*64+nf*16..]
    #pragma unroll
    for (int i = 0; i < 4; ++i)
        #pragma unroll
        for (int j = 0; j < 4; ++j)
            acc2[i][j] = (f32x4){0.f, 0.f, 0.f, 0.f};

    float sumA = 0.f;
    const float bias_c = bias[wc * 16 + g];

    // ---- prologue: stage chunk 0 into xs[0] ----
    {
        const int nb0 = slice * CHUNKS * NBC;
        float4 s0[4];
        #pragma unroll
        for (int it = 0; it < 4; ++it) {
            int o  = it * 4096 + tid * 8;
            int n  = o >> 10;
            int sw = ((n & 7) << 4) ^ (((n >> 3) & 1) << 6);
            int c0 = ((o & 1023) ^ sw) >> 1;
            s0[it] = *(const float4*)(xb + (size_t)(nb0 + n) * C_ + c0);
        }
        #pragma unroll
        for (int it = 0; it < 4; ++it) {
            int o = it * 4096 + tid * 8;
            u32x2 p; p[0] = cvt2(s0[it].x, s0[it].y); p[1] = cvt2(s0[it].z, s0[it].w);
            *(u32x2*)(&xs[0][0] + o) = p;
        }
    }

    for (int t = 0; t < CHUNKS; ++t) {
        const int cur = t & 1, nxt = cur ^ 1;
        const bool hasNext = (t + 1 < CHUNKS);
        const int nb2 = (slice * CHUNKS + t + 1) * NBC;

        float4 stg[4];
        auto issue = [&](int it) {
            int o  = it * 4096 + tid * 8;
            int n  = o >> 10;
            int sw = ((n & 7) << 4) ^ (((n >> 3) & 1) << 6);
            int c0 = ((o & 1023) ^ sw) >> 1;
            stg[it] = *(const float4*)(xb + (size_t)(nb2 + n) * C_ + c0);
        };

        // bq loads FIRST (L2, ~200cy), then stg01 (HBM, ~900cy): consuming
        // bq in GEMM1 then waits only a counted vmcnt(2) that does NOT drain
        // the younger staging loads.
        bf16x8 bq[8];
        #pragma unroll
        for (int ks = 0; ks < 8; ++ks)
            bq[ks] = *(const bf16x8*)(wp + ks * 32);

        if (hasNext) { issue(0); issue(1); }

        bar_lds();   // B0: xs[cur] visible; iter t-1 fully done

        // ---------- GEMM1 (C-split): partial logits[16 rows][16 clusters] ----------
        f32x4 acc1 = (f32x4){0.f, 0.f, 0.f, 0.f};
        #pragma unroll
        for (int ks = 0; ks < 8; ++ks) {
            int off = ((g << 10) + ((wr * 256 + ks * 32 + q * 8) << 1))
                      ^ ((g & 7) << 4) ^ (((g >> 3) & 1) << 6);
            bf16x8 a = *(const bf16x8*)(&xs[cur][0] + off);   // ds_read_b128
            acc1 = __builtin_amdgcn_mfma_f32_16x16x32_bf16(a, bq[ks], acc1, 0, 0, 0);
        }

        if (hasNext) { issue(2); issue(3); }

        // ---------- cross-half reduce + softmax (wr==0 waves) ----------
        if (wr == 1) {
            #pragma unroll
            for (int r = 0; r < 4; ++r)
                red1[q * 4 + r][wc * 16 + g] = acc1[r];
        }
        bar_lds();   // B1

        float ev[4];
        if (wr == 0) {
            #pragma unroll
            for (int r = 0; r < 4; ++r) {
                float tot = acc1[r] + red1[q * 4 + r][wc * 16 + g] + bias_c;
                ev[r] = __expf(tot);
                float s = ev[r];
                s += __shfl_xor(s, 1);
                s += __shfl_xor(s, 2);
                s += __shfl_xor(s, 4);
                s += __shfl_xor(s, 8);
                if (g == 0) red[q * 4 + r][wc] = s;
            }
        }
        bar_lds();   // B2

        if (wr == 0) {
            #pragma unroll
            for (int r = 0; r < 4; ++r) {
                int row = q * 4 + r;
                float4 rv = *(const float4*)red[row];
                float s = (rv.x + rv.y) + (rv.z + rv.w);
                float a = ev[r] / s;
                sumA += a;
                assgnT[wc * 16 + g][row] = (uint16_t)f32_bf16(a);
            }
        }
        bar_lds();   // B3: assgnT ready

        // ---------- GEMM2: acc2 += assgnT @ x_chunk (K=16; upper A-half zero) ----------
        u32x2 lo[4], hi[4];
        {
            const int nr   = (q & 1) * 8 + (g >> 2);          // q>=2 mirrored (values x0)
            const int swz  = ((nr & 7) << 4) ^ (((nr >> 3) & 1) << 6);
            const int raw0 = (nr << 10) + ((4 * (g & 3)) << 1);
            const int bufb = cur * (NBC * 1024);
            #pragma unroll
            for (int nf = 0; nf < 4; ++nf) {
                int raw = raw0 + ((w * 64 + nf * 16) << 1);
                uint32_t ad1 = (uint32_t)((raw ^ swz) + bufb);
                uint32_t ad2 = ad1 ^ 0x40u;                   // row +4 swizzle flip
                asm volatile("ds_read_b64_tr_b16 %0, %1"
                             : "=v"(lo[nf]) : "v"(ad1));
                asm volatile("ds_read_b64_tr_b16 %0, %1 offset:4096"
                             : "=v"(hi[nf]) : "v"(ad2));
            }
        }
        asm volatile("s_waitcnt lgkmcnt(0)" ::: "memory");
        __builtin_amdgcn_sched_barrier(0);

        // mf-outer: one live A-frag (saves 12 VGPR vs afr[4])
        #pragma unroll
        for (int mf = 0; mf < 4; ++mf) {
            bf16x8 afr;
            if (q < 2) afr = *(const bf16x8*)&assgnT[mf * 16 + g][q * 8];
            else       afr = (bf16x8){0,0,0,0,0,0,0,0};
            #pragma unroll
            for (int nf = 0; nf < 4; ++nf) {
                union { struct { u32x2 a, b; } p; bf16x8 v; } fr;
                fr.p.a = lo[nf]; fr.p.b = hi[nf];
                acc2[mf][nf] = __builtin_amdgcn_mfma_f32_16x16x32_bf16(afr, fr.v, acc2[mf][nf], 0, 0, 0);
            }
        }

        // ---------- write staged chunk t+1 into the other buffer ----------
        // compiler inserts counted s_waitcnt vmcnt before first use of stg;
        // write in issue order (0 first) so waits are already satisfied.
        if (hasNext) {
            #pragma unroll
            for (int it = 0; it < 4; ++it) {
                int o = it * 4096 + tid * 8;
                u32x2 p; p[0] = cvt2(stg[it].x, stg[it].y); p[1] = cvt2(stg[it].z, stg[it].w);
                *(u32x2*)(&xs[nxt][0] + o) = p;
            }
        }
        // next B0 makes it visible
    }

    // ---------- epilogue ----------
    if (wr == 0) {
        float st = sumA;
        st += __shfl_xor(st, 16);
        st += __shfl_xor(st, 32);
        if (q == 0) atomicAdd(&sum_ws[b * K_ + wc * 16 + g], st);
    }

    if (STORE_PARTIALS) {
        // partials layout: [slice][b][chn][cluster] bf16 — per-thread 4 clusters pack to 8B
        uint16_t* pb = partials + ((size_t)slice * B_ + b) * ((size_t)C_ * K_);
        #pragma unroll
        for (int mf = 0; mf < 4; ++mf)
            #pragma unroll
            for (int nf = 0; nf < 4; ++nf) {
                f32x4 v = acc2[mf][nf];
                u32x2 p; p[0] = cvt2(v[0], v[1]); p[1] = cvt2(v[2], v[3]);
                int chn = w * 64 + nf * 16 + g;
                int cl  = mf * 16 + q * 4;
                __builtin_nontemporal_store(p, (u32x2*)(pb + (size_t)chn * K_ + cl));
            }
    } else {
        float* ob = out + (size_t)b * K_ * C_;
        #pragma unroll
        for (int mf = 0; mf < 4; ++mf)
            #pragma unroll
            for (int nf = 0; nf < 4; ++nf)
                #pragma unroll
                for (int r = 0; r < 4; ++r) {
                    int cluster = mf * 16 + q * 4 + r;
                    int chn = w * 64 + nf * 16 + g;
                    atomicAdd(&ob[(size_t)cluster * C_ + chn], acc2[mf][nf][r]);
                }
    }
}

// ---- reduce partials + subtract centers + /N (store path) ----
__global__ void vlad_reduce(const uint16_t* __restrict__ partials,
                            const float* __restrict__ sum_ws,
                            const float* __restrict__ centers,
                            float* __restrict__ out)
{
    int idx = blockIdx.x * blockDim.x + threadIdx.x;   // (b, chn, k8) : 65536 threads
    int k8  = idx & 7;
    int chn = (idx >> 3) & (C_ - 1);
    int b   = idx >> 12;

    float acc[8] = {0,0,0,0,0,0,0,0};
    const uint16_t* p = partials + (size_t)b * ((size_t)C_ * K_) + (size_t)chn * K_ + k8 * 8;
    #pragma unroll 4
    for (int s = 0; s < SLICES; ++s) {
        bf16x8 v = *(const bf16x8*)(p + (size_t)s * ((size_t)B_ * C_ * K_));
        #pragma unroll
        for (int j = 0; j < 8; ++j)
            acc[j] += bf16_f32((uint16_t)v[j]);
    }
    const float inv = 1.0f / (float)N_;
    #pragma unroll
    for (int j = 0; j < 8; ++j) {
        int k = k8 * 8 + j;
        float r = (acc[j] - sum_ws[b * K_ + k] * centers[(size_t)k * C_ + chn]) * inv;
        out[((size_t)b * K_ + k) * C_ + chn] = r;
    }
}

// ---- final for atomic fallback path ----
__global__ void vlad_final(float* __restrict__ out, const float* __restrict__ sum_ws,
                           const float* __restrict__ centers)
{
    int idx = blockIdx.x * blockDim.x + threadIdx.x;   // over B*K*C/4
    int c4 = idx & (C_ / 4 - 1);
    int k  = (idx >> 7) & (K_ - 1);
    int b  = idx >> 13;
    float s = sum_ws[b * K_ + k];
    float4 o  = ((float4*)out)[idx];
    float4 ce = ((const float4*)centers)[k * (C_ / 4) + c4];
    const float inv = 1.0f / (float)N_;
    o.x = (o.x - s * ce.x) * inv;
    o.y = (o.y - s * ce.y) * inv;
    o.z = (o.z - s * ce.z) * inv;
    o.w = (o.w - s * ce.w) * inv;
    ((float4*)out)[idx] = o;
}

extern "C" void kernel_launch(void* const* d_in, const int* in_sizes, int n_in,
                              void* d_out, int out_size, void* d_ws, size_t ws_size,
                              hipStream_t stream)
{
    const float* x       = (const float*)d_in[0];
    const float* kern    = (const float*)d_in[1];
    const float* bias    = (const float*)d_in[2];
    const float* centers = (const float*)d_in[3];
    float* out = (float*)d_out;

    uint16_t* wkt    = (uint16_t*)d_ws;
    float*    sum_ws = (float*)((char*)d_ws + SUMWS_OFF);
    uint16_t* parts  = (uint16_t*)((char*)d_ws + PART_OFF);

    hipMemsetAsync(sum_ws, 0, SUMWS_BYTES, stream);
    prep_wkt<<<(K_ * C_) / 256, 256, 0, stream>>>(kern, wkt);

    if (ws_size >= WS_NEEDED) {
        vlad_main<true><<<dim3(B_, SLICES), 512, 0, stream>>>(x, wkt, bias, out, sum_ws, parts);
        vlad_reduce<<<(B_ * C_ * K_ / 8) / 256, 256, 0, stream>>>(parts, sum_ws, centers, out);
    } else {
        hipMemsetAsync(out, 0, sizeof(float) * (size_t)B_ * K_ * C_, stream);
        vlad_main<false><<<dim3(B_, SLICES), 512, 0, stream>>>(x, wkt, bias, out, sum_ws, parts);
        vlad_final<<<(B_ * K_ * C_ / 4) / 256, 256, 0, stream>>>(out, sum_ws, centers);
    }
}

// Round 4
// 93.325 us; speedup vs baseline: 1.9026x; 1.9026x over previous
//
#include <hip/hip_runtime.h>
#include <hip/hip_bf16.h>
#include <stdint.h>
#include <stddef.h>

#define B_   16
#define N_   6272     // T*H*W = 32*14*14
#define C_   512
#define K_   64
#define NBC  32       // rows per chunk (R4: was 16 — halves sync rounds/byte)
#define SLICES 28     // blocks per batch
#define CHUNKS 7      // 28*7*32 = 6272

#define WKT_BYTES   ((size_t)K_ * C_ * sizeof(uint16_t))          // 64 KB
#define SUMWS_OFF   WKT_BYTES
#define SUMWS_BYTES ((size_t)B_ * K_ * sizeof(float))             // 4 KB
#define PART_OFF    (0x11000u)                                    // 68 KB, 4KB-aligned
#define PART_ELEMS  ((size_t)SLICES * B_ * C_ * K_)               // bf16 elements
#define WS_NEEDED   (PART_OFF + PART_ELEMS * sizeof(uint16_t))    // ~29.4 MB

typedef float f32x4 __attribute__((ext_vector_type(4)));
typedef short bf16x8 __attribute__((ext_vector_type(8)));
typedef uint32_t u32x2 __attribute__((ext_vector_type(2)));

__device__ __forceinline__ uint32_t cvt2(float lo, float hi) {
    __hip_bfloat162 h = __float22bfloat162_rn(float2{lo, hi});
    union { __hip_bfloat162 h; uint32_t u; } v; v.h = h;
    return v.u;
}

__device__ __forceinline__ short f32_bf16(float f) {
    union { float f; uint32_t u; } v; v.f = f;
    return (short)((v.u + 0x7FFFu + ((v.u >> 16) & 1u)) >> 16);  // RNE
}

__device__ __forceinline__ float bf16_f32(uint16_t u) {
    union { uint32_t u; float f; } v; v.u = (uint32_t)u << 16;
    return v.f;
}

// LDS-only barrier: drains lgkm (ds ops) but leaves global loads in flight.
// The "memory" clobbers also fence LICM: per-chunk bq reloads cannot be
// hoisted out of the loop across these barriers.
__device__ __forceinline__ void bar_lds() {
    asm volatile("s_waitcnt lgkmcnt(0)" ::: "memory");
    __builtin_amdgcn_s_barrier();
    asm volatile("" ::: "memory");
    __builtin_amdgcn_sched_barrier(0);
}

// swizzled LDS byte offset of bf16 element x[n][c] within a 32-row buffer:
//   byte = (n*1024 + c*2) ^ ((n&7)<<4) ^ (((n>>3)&1)<<6)
// (identical to the 16-row formula; bit4 of n only shifts the base by 16KB)

// ---- prep: WkT[k][c] = bf16(kernel[c][k]) ----
__global__ void prep_wkt(const float* __restrict__ kern, uint16_t* __restrict__ wkt) {
    int idx = blockIdx.x * blockDim.x + threadIdx.x;   // 0..32767
    int k = idx >> 9, c = idx & 511;
    wkt[idx] = (uint16_t)f32_bf16(kern[c * K_ + k]);
}

// ---- main fused kernel: 8 waves, dbuf LDS, NBC=32 (R4) ----
// launch_bounds(512,2): empirically 128-VGPR budget & 2 blocks/CU (R3
// post-mortem: the 2nd arg acts as min-blocks/CU on this toolchain;
// (512,4) forced 64 VGPR -> massive stg/acc2 scratch spill, 177us).
// NBC=32: 4 barriers per 32 rows (was 8), full-K GEMM2 (was half-zero),
// 2x HBM burst per sync. VGPR diet: bq reloaded per-chunk from L2,
// stg[8] issued 4+4 with writes split around GEMM2.
template <bool STORE_PARTIALS>
__global__ __launch_bounds__(512, 2)
void vlad_main(const float* __restrict__ x, const uint16_t* __restrict__ wkt,
               const float* __restrict__ bias, float* __restrict__ out,
               float* __restrict__ sum_ws, uint16_t* __restrict__ partials)
{
    const int b = blockIdx.x, slice = blockIdx.y;
    const int tid = threadIdx.x;
    const int w    = tid >> 6;       // wave 0..7
    const int lane = tid & 63;
    const int g = lane & 15, q = lane >> 4;
    const int wr = w >> 2;           // C-half for GEMM1 (0: ch 0..255, 1: 256..511)
    const int wc = w & 3;            // cluster group for GEMM1

    // xs FIRST: tr-read asm assumes LDS offset 0 for xs
    __shared__ __align__(16) uint8_t  xs[2][NBC * 1024];   // 2 x 32KB swizzled bf16
    __shared__ __align__(16) uint16_t assgnT[K_][NBC];     // [cluster][row] bf16, 4KB
    __shared__ __align__(16) float    red1[NBC][K_];       // partial logits, 8KB
    __shared__ __align__(16) float    red[NBC][4];         // row softmax sums

    const float* xb = x + (size_t)b * N_ * C_;

    // GEMM1 B-frag base: WkT[wc*16+g][wr*256 + ks*32 + q*8]; reloaded
    // per-chunk (64KB L2-resident, shared by all blocks) to save 32 VGPRs.
    const uint16_t* wp = wkt + (size_t)(wc * 16 + g) * C_ + wr * 256 + q * 8;

    f32x4 acc2[4][4];   // [mf: clusters 16mf..][nf: channels w*64+nf*16..]
    #pragma unroll
    for (int i = 0; i < 4; ++i)
        #pragma unroll
        for (int j = 0; j < 4; ++j)
            acc2[i][j] = (f32x4){0.f, 0.f, 0.f, 0.f};

    float sumA = 0.f;
    const float bias_c = bias[wc * 16 + g];

    // ---- prologue: stage chunk 0 into xs[0] (32KB, 8 x 4KB) ----
    {
        const int nb0 = slice * CHUNKS * NBC;
        float4 s0[8];
        #pragma unroll
        for (int it = 0; it < 8; ++it) {
            int o  = it * 4096 + tid * 8;
            int n  = o >> 10;
            int sw = ((n & 7) << 4) ^ (((n >> 3) & 1) << 6);
            int c0 = ((o & 1023) ^ sw) >> 1;
            s0[it] = *(const float4*)(xb + (size_t)(nb0 + n) * C_ + c0);
        }
        #pragma unroll
        for (int it = 0; it < 8; ++it) {
            int o = it * 4096 + tid * 8;
            u32x2 p; p[0] = cvt2(s0[it].x, s0[it].y); p[1] = cvt2(s0[it].z, s0[it].w);
            *(u32x2*)(&xs[0][0] + o) = p;
        }
    }

    for (int t = 0; t < CHUNKS; ++t) {
        const int cur = t & 1, nxt = cur ^ 1;
        const bool hasNext = (t + 1 < CHUNKS);
        const int nb2 = (slice * CHUNKS + t + 1) * NBC;

        float4 stg[8];
        auto issue = [&](int it) {
            int o  = it * 4096 + tid * 8;
            int n  = o >> 10;
            int sw = ((n & 7) << 4) ^ (((n >> 3) & 1) << 6);
            int c0 = ((o & 1023) ^ sw) >> 1;
            stg[it] = *(const float4*)(xb + (size_t)(nb2 + n) * C_ + c0);
        };
        auto wr_stg = [&](int it) {
            int o = it * 4096 + tid * 8;
            u32x2 p; p[0] = cvt2(stg[it].x, stg[it].y); p[1] = cvt2(stg[it].z, stg[it].w);
            *(u32x2*)(&xs[nxt][0] + o) = p;
        };

        // bq loads FIRST (L2 ~200cy), then stg0..3 (HBM ~900cy): GEMM1's
        // bq consumption waits a counted vmcnt that leaves stg in flight.
        bf16x8 bq[8];
        #pragma unroll
        for (int ks = 0; ks < 8; ++ks)
            bq[ks] = *(const bf16x8*)(wp + ks * 32);

        if (hasNext) { issue(0); issue(1); issue(2); issue(3); }

        bar_lds();   // B0: xs[cur] visible; iter t-1 fully done

        // ---------- GEMM1 (C-split): logits[32 rows][16 clusters], 2 row-groups ----------
        f32x4 acc1[2];
        acc1[0] = (f32x4){0.f, 0.f, 0.f, 0.f};
        acc1[1] = (f32x4){0.f, 0.f, 0.f, 0.f};
        #pragma unroll
        for (int ks = 0; ks < 8; ++ks) {
            int off = ((g << 10) + ((wr * 256 + ks * 32 + q * 8) << 1))
                      ^ ((g & 7) << 4) ^ (((g >> 3) & 1) << 6);
            bf16x8 a0 = *(const bf16x8*)(&xs[cur][0] + off);            // rows 0..15
            bf16x8 a1 = *(const bf16x8*)(&xs[cur][0] + off + 16384);    // rows 16..31
            acc1[0] = __builtin_amdgcn_mfma_f32_16x16x32_bf16(a0, bq[ks], acc1[0], 0, 0, 0);
            acc1[1] = __builtin_amdgcn_mfma_f32_16x16x32_bf16(a1, bq[ks], acc1[1], 0, 0, 0);
        }

        if (hasNext) { issue(4); issue(5); issue(6); issue(7); }   // bq dead; regs reused

        // ---------- cross-half reduce + softmax (wr==0 waves) ----------
        if (wr == 1) {
            #pragma unroll
            for (int rg = 0; rg < 2; ++rg)
                #pragma unroll
                for (int r = 0; r < 4; ++r)
                    red1[rg * 16 + q * 4 + r][wc * 16 + g] = acc1[rg][r];
        }
        bar_lds();   // B1

        // write stg0..3 into xs[nxt] (free all chunk; counted vmcnt(4) wait)
        if (hasNext) { wr_stg(0); wr_stg(1); wr_stg(2); wr_stg(3); }

        float ev[2][4];
        if (wr == 0) {
            #pragma unroll
            for (int rg = 0; rg < 2; ++rg)
                #pragma unroll
                for (int r = 0; r < 4; ++r) {
                    float tot = acc1[rg][r] + red1[rg * 16 + q * 4 + r][wc * 16 + g] + bias_c;
                    ev[rg][r] = __expf(tot);
                    float s = ev[rg][r];
                    s += __shfl_xor(s, 1);
                    s += __shfl_xor(s, 2);
                    s += __shfl_xor(s, 4);
                    s += __shfl_xor(s, 8);
                    if (g == 0) red[rg * 16 + q * 4 + r][wc] = s;
                }
        }
        bar_lds();   // B2

        if (wr == 0) {
            #pragma unroll
            for (int rg = 0; rg < 2; ++rg)
                #pragma unroll
                for (int r = 0; r < 4; ++r) {
                    int row = rg * 16 + q * 4 + r;
                    float4 rv = *(const float4*)red[row];
                    float s = (rv.x + rv.y) + (rv.z + rv.w);
                    float a = ev[rg][r] / s;
                    sumA += a;
                    assgnT[wc * 16 + g][row] = (uint16_t)f32_bf16(a);
                }
        }
        bar_lds();   // B3: assgnT ready

        // ---------- GEMM2: acc2 += assgnT @ x_chunk (full K=32) ----------
        u32x2 lo[4], hi[4];
        {
            const int nr   = q * 8 + (g >> 2);                // rows 0..27 (+4 via hi)
            const int swz  = ((nr & 7) << 4) ^ (((nr >> 3) & 1) << 6);
            const int raw0 = (nr << 10) + ((4 * (g & 3)) << 1);
            const int bufb = cur * (NBC * 1024);
            #pragma unroll
            for (int nf = 0; nf < 4; ++nf) {
                int raw = raw0 + ((w * 64 + nf * 16) << 1);
                uint32_t ad1 = (uint32_t)((raw ^ swz) + bufb);
                uint32_t ad2 = ad1 ^ 0x40u;                   // row +4 swizzle flip (nr&7<4 always)
                asm volatile("ds_read_b64_tr_b16 %0, %1"
                             : "=v"(lo[nf]) : "v"(ad1));
                asm volatile("ds_read_b64_tr_b16 %0, %1 offset:4096"
                             : "=v"(hi[nf]) : "v"(ad2));
            }
        }
        asm volatile("s_waitcnt lgkmcnt(0)" ::: "memory");
        __builtin_amdgcn_sched_barrier(0);

        // mf-outer: one live A-frag; full K (no zero half)
        #pragma unroll
        for (int mf = 0; mf < 4; ++mf) {
            bf16x8 afr = *(const bf16x8*)&assgnT[mf * 16 + g][q * 8];
            #pragma unroll
            for (int nf = 0; nf < 4; ++nf) {
                union { struct { u32x2 a, b; } p; bf16x8 v; } fr;
                fr.p.a = lo[nf]; fr.p.b = hi[nf];
                acc2[mf][nf] = __builtin_amdgcn_mfma_f32_16x16x32_bf16(afr, fr.v, acc2[mf][nf], 0, 0, 0);
            }
        }

        // write stg4..7 (loads have had GEMM1-tail+softmax+GEMM2 to land)
        if (hasNext) { wr_stg(4); wr_stg(5); wr_stg(6); wr_stg(7); }
        // next B0 makes xs[nxt] visible
    }

    // ---------- epilogue ----------
    if (wr == 0) {
        float st = sumA;
        st += __shfl_xor(st, 16);
        st += __shfl_xor(st, 32);
        if (q == 0) atomicAdd(&sum_ws[b * K_ + wc * 16 + g], st);
    }

    if (STORE_PARTIALS) {
        // partials layout: [slice][b][chn][cluster] bf16 — per-thread 4 clusters pack to 8B
        uint16_t* pb = partials + ((size_t)slice * B_ + b) * ((size_t)C_ * K_);
        #pragma unroll
        for (int mf = 0; mf < 4; ++mf)
            #pragma unroll
            for (int nf = 0; nf < 4; ++nf) {
                f32x4 v = acc2[mf][nf];
                u32x2 p; p[0] = cvt2(v[0], v[1]); p[1] = cvt2(v[2], v[3]);
                int chn = w * 64 + nf * 16 + g;
                int cl  = mf * 16 + q * 4;
                __builtin_nontemporal_store(p, (u32x2*)(pb + (size_t)chn * K_ + cl));
            }
    } else {
        float* ob = out + (size_t)b * K_ * C_;
        #pragma unroll
        for (int mf = 0; mf < 4; ++mf)
            #pragma unroll
            for (int nf = 0; nf < 4; ++nf)
                #pragma unroll
                for (int r = 0; r < 4; ++r) {
                    int cluster = mf * 16 + q * 4 + r;
                    int chn = w * 64 + nf * 16 + g;
                    atomicAdd(&ob[(size_t)cluster * C_ + chn], acc2[mf][nf][r]);
                }
    }
}

// ---- reduce partials + subtract centers + /N (store path) ----
__global__ void vlad_reduce(const uint16_t* __restrict__ partials,
                            const float* __restrict__ sum_ws,
                            const float* __restrict__ centers,
                            float* __restrict__ out)
{
    int idx = blockIdx.x * blockDim.x + threadIdx.x;   // (b, chn, k8) : 65536 threads
    int k8  = idx & 7;
    int chn = (idx >> 3) & (C_ - 1);
    int b   = idx >> 12;

    float acc[8] = {0,0,0,0,0,0,0,0};
    const uint16_t* p = partials + (size_t)b * ((size_t)C_ * K_) + (size_t)chn * K_ + k8 * 8;
    #pragma unroll 4
    for (int s = 0; s < SLICES; ++s) {
        bf16x8 v = *(const bf16x8*)(p + (size_t)s * ((size_t)B_ * C_ * K_));
        #pragma unroll
        for (int j = 0; j < 8; ++j)
            acc[j] += bf16_f32((uint16_t)v[j]);
    }
    const float inv = 1.0f / (float)N_;
    #pragma unroll
    for (int j = 0; j < 8; ++j) {
        int k = k8 * 8 + j;
        float r = (acc[j] - sum_ws[b * K_ + k] * centers[(size_t)k * C_ + chn]) * inv;
        out[((size_t)b * K_ + k) * C_ + chn] = r;
    }
}

// ---- final for atomic fallback path ----
__global__ void vlad_final(float* __restrict__ out, const float* __restrict__ sum_ws,
                           const float* __restrict__ centers)
{
    int idx = blockIdx.x * blockDim.x + threadIdx.x;   // over B*K*C/4
    int c4 = idx & (C_ / 4 - 1);
    int k  = (idx >> 7) & (K_ - 1);
    int b  = idx >> 13;
    float s = sum_ws[b * K_ + k];
    float4 o  = ((float4*)out)[idx];
    float4 ce = ((const float4*)centers)[k * (C_ / 4) + c4];
    const float inv = 1.0f / (float)N_;
    o.x = (o.x - s * ce.x) * inv;
    o.y = (o.y - s * ce.y) * inv;
    o.z = (o.z - s * ce.z) * inv;
    o.w = (o.w - s * ce.w) * inv;
    ((float4*)out)[idx] = o;
}

extern "C" void kernel_launch(void* const* d_in, const int* in_sizes, int n_in,
                              void* d_out, int out_size, void* d_ws, size_t ws_size,
                              hipStream_t stream)
{
    const float* x       = (const float*)d_in[0];
    const float* kern    = (const float*)d_in[1];
    const float* bias    = (const float*)d_in[2];
    const float* centers = (const float*)d_in[3];
    float* out = (float*)d_out;

    uint16_t* wkt    = (uint16_t*)d_ws;
    float*    sum_ws = (float*)((char*)d_ws + SUMWS_OFF);
    uint16_t* parts  = (uint16_t*)((char*)d_ws + PART_OFF);

    hipMemsetAsync(sum_ws, 0, SUMWS_BYTES, stream);
    prep_wkt<<<(K_ * C_) / 256, 256, 0, stream>>>(kern, wkt);

    if (ws_size >= WS_NEEDED) {
        vlad_main<true><<<dim3(B_, SLICES), 512, 0, stream>>>(x, wkt, bias, out, sum_ws, parts);
        vlad_reduce<<<(B_ * C_ * K_ / 8) / 256, 256, 0, stream>>>(parts, sum_ws, centers, out);
    } else {
        hipMemsetAsync(out, 0, sizeof(float) * (size_t)B_ * K_ * C_, stream);
        vlad_main<false><<<dim3(B_, SLICES), 512, 0, stream>>>(x, wkt, bias, out, sum_ws, parts);
        vlad_final<<<(B_ * K_ * C_ / 4) / 256, 256, 0, stream>>>(out, sum_ws, centers);
    }
}